// Round 1
// baseline (181.789 us; speedup 1.0000x reference)
//
#include <hip/hip_runtime.h>
#include <stdint.h>

// Problem constants (reference: B=2, C=4, SPATIAL=(128,128,128), N_PTS=32, THR=0.5)
#define Bn 2
#define Cn 4
#define Sn (128 * 128 * 128)
#define NPTS 32
#define NBINS 1025          // probs in (0.5, 1] -> one binade; (bits-0x3F000000)>>13 in [0,1024]
#define THRf 0.5f
#define SEL_LDS 4096        // LDS candidate cache in select kernel

__device__ __forceinline__ int bin_of(float p) {
    // p in (0.5, 1]; bits monotone in value within the binade (+1.0 endpoint)
    unsigned int u = __float_as_uint(p);
    return (int)((u - 0x3F000000u) >> 13);
}

// Softmax over the 4 classes at voxel i of batch b; returns argmax class and its prob.
// Mirrors jax.nn.softmax: exp(x - max) / sum(exp(x - max)), sequential sum c=0..3.
__device__ __forceinline__ void softmax_argmax(const float* __restrict__ base, int i,
                                               int* cm_out, float* p_out) {
    float l0 = base[i];
    float l1 = base[i + Sn];
    float l2 = base[i + 2 * Sn];
    float l3 = base[i + 3 * Sn];
    float m = fmaxf(fmaxf(l0, l1), fmaxf(l2, l3));
    float e0 = expf(l0 - m);
    float e1 = expf(l1 - m);
    float e2 = expf(l2 - m);
    float e3 = expf(l3 - m);
    float s = ((e0 + e1) + e2) + e3;
    float em = e0; int cm = 0;
    if (e1 > em) { em = e1; cm = 1; }
    if (e2 > em) { em = e2; cm = 2; }
    if (e3 > em) { em = e3; cm = 3; }
    // Only the argmax class can have p > 0.5 (probs sum to 1).
    *cm_out = cm;
    *p_out = em / s;   // identical float division to reference's p_c = e_c / s
}

// Pass 1: per-(b,c) radix histogram of candidate probs (p > 0.5)
__global__ __launch_bounds__(256) void hist_kernel(const float* __restrict__ logits,
                                                   unsigned int* __restrict__ hist,
                                                   int per_block) {
    __shared__ unsigned int lh[Cn * NBINS];
    const int b = blockIdx.y;
    for (int j = threadIdx.x; j < Cn * NBINS; j += blockDim.x) lh[j] = 0u;
    __syncthreads();
    const float* base = logits + (size_t)b * Cn * Sn;
    const int start = blockIdx.x * per_block;
    const int end = min(Sn, start + per_block);
    for (int i = start + threadIdx.x; i < end; i += blockDim.x) {
        int cm; float p;
        softmax_argmax(base, i, &cm, &p);
        if (p > THRf) atomicAdd(&lh[cm * NBINS + bin_of(p)], 1u);
    }
    __syncthreads();
    unsigned int* gh = hist + (size_t)b * Cn * NBINS;
    for (int j = threadIdx.x; j < Cn * NBINS; j += blockDim.x) {
        unsigned int v = lh[j];
        if (v) atomicAdd(&gh[j], v);
    }
}

// Pass 2: per-(b,c) find cutoff bin (cumulative-from-top >= 32) and valid_n = min(32, total)
__global__ void cutoff_kernel(const unsigned int* __restrict__ hist,
                              unsigned int* __restrict__ cutoff,
                              unsigned int* __restrict__ validn) {
    int bc = threadIdx.x;
    if (bc >= Bn * Cn) return;
    const unsigned int* h = hist + (size_t)bc * NBINS;
    unsigned int acc = 0, total = 0;
    int T = 0; bool found = false;
    for (int bin = NBINS - 1; bin >= 0; --bin) {
        unsigned int v = h[bin];
        total += v;
        if (!found) {
            acc += v;
            if (acc >= NPTS) { T = bin; found = true; }
        }
    }
    cutoff[bc] = (unsigned int)(found ? T : 0);
    validn[bc] = total < NPTS ? total : NPTS;
}

// Pass 3: collect all candidates with bin >= cutoff (superset of the true top-32)
__global__ __launch_bounds__(256) void collect_kernel(const float* __restrict__ logits,
                                                      const unsigned int* __restrict__ cutoff,
                                                      unsigned int* __restrict__ cnt,
                                                      uint2* __restrict__ cand,
                                                      int cap, int per_block) {
    __shared__ unsigned int cut[Cn];
    const int b = blockIdx.y;
    if (threadIdx.x < Cn) cut[threadIdx.x] = cutoff[b * Cn + threadIdx.x];
    __syncthreads();
    const float* base = logits + (size_t)b * Cn * Sn;
    const int start = blockIdx.x * per_block;
    const int end = min(Sn, start + per_block);
    for (int i = start + threadIdx.x; i < end; i += blockDim.x) {
        int cm; float p;
        softmax_argmax(base, i, &cm, &p);
        if (p > THRf) {
            int bin = bin_of(p);
            if ((unsigned int)bin >= cut[cm]) {
                int bc = b * Cn + cm;
                unsigned int pos = atomicAdd(&cnt[bc], 1u);
                if (pos < (unsigned int)cap)
                    cand[(size_t)bc * cap + pos] = make_uint2(__float_as_uint(p), (unsigned int)i);
            }
        }
    }
}

// Pass 4: exact rank selection among collected candidates.
// beats(o, e): o.value > e.value, or equal value and lower index (jax top_k tie-break).
__global__ __launch_bounds__(256) void select_kernel(const unsigned int* __restrict__ cnt,
                                                     const uint2* __restrict__ cand,
                                                     const unsigned int* __restrict__ validn,
                                                     uint2* __restrict__ topk,
                                                     int cap) {
    const int bc = blockIdx.x;
    const int n = min((int)cnt[bc], cap);
    const int vn = (int)validn[bc];
    const uint2* src = cand + (size_t)bc * cap;
    __shared__ uint2 sc[SEL_LDS];
    const bool fits = (n <= SEL_LDS);
    if (fits) {
        for (int j = threadIdx.x; j < n; j += blockDim.x) sc[j] = src[j];
        __syncthreads();
    }
    for (int t = threadIdx.x; t < n; t += blockDim.x) {
        uint2 e = fits ? sc[t] : src[t];
        int rank = 0;
        if (fits) {
            for (int j = 0; j < n; ++j) {
                uint2 o = sc[j];
                rank += (int)((o.x > e.x) || (o.x == e.x && o.y < e.y));
            }
        } else {
            for (int j = 0; j < n; ++j) {
                uint2 o = src[j];
                rank += (int)((o.x > e.x) || (o.x == e.x && o.y < e.y));
            }
        }
        if (rank < vn) topk[bc * NPTS + rank] = e;
    }
}

// Pass 5: compact per-batch in class order [1,2,3,0], unravel coords, pad with -1/0.
// Output layout: coords int32 (2,128,3) flat, then labels int32 (2,128).
__global__ void emit_kernel(const uint2* __restrict__ topk,
                            const unsigned int* __restrict__ validn,
                            int* __restrict__ out) {
    const int b = blockIdx.x;
    __shared__ int pre[Cn + 1];
    if (threadIdx.x == 0) {
        int acc = 0;
        for (int oc = 0; oc < Cn; ++oc) {
            pre[oc] = acc;
            int c = (oc + 1) & 3;  // order = [1,2,3,0]
            acc += (int)validn[b * Cn + c];
        }
        pre[Cn] = acc;
    }
    __syncthreads();
    const int j = threadIdx.x;  // 0..127
    int label = -1, z = 0, y = 0, x = 0;
    if (j < pre[Cn]) {
        int oc = 0;
        while (j >= pre[oc + 1]) ++oc;
        int c = (oc + 1) & 3;
        int r = j - pre[oc];
        uint2 e = topk[(b * Cn + c) * NPTS + r];
        int idx = (int)e.y;
        z = idx >> 14;          // idx / (128*128)
        y = (idx >> 7) & 127;   // (idx / 128) % 128
        x = idx & 127;          // idx % 128
        label = c;
    }
    int* coords = out;                       // 2*128*3 = 768 ints
    int* labels = out + Bn * Cn * NPTS * 3;  // then 2*128 = 256 ints
    int base = b * Cn * NPTS + j;
    coords[base * 3 + 0] = z;
    coords[base * 3 + 1] = y;
    coords[base * 3 + 2] = x;
    labels[base] = label;
}

extern "C" void kernel_launch(void* const* d_in, const int* in_sizes, int n_in,
                              void* d_out, int out_size, void* d_ws, size_t ws_size,
                              hipStream_t stream) {
    const float* logits = (const float*)d_in[0];
    int* out = (int*)d_out;

    // Workspace layout
    unsigned int* hist = (unsigned int*)d_ws;            // 8 * 1025 u32 = 32800 B
    unsigned int* cnt = hist + Bn * Cn * NBINS;          // 8 u32
    unsigned int* cutoff = cnt + Bn * Cn;                // 8 u32
    unsigned int* validn = cutoff + Bn * Cn;             // 8 u32
    uint2* topk = (uint2*)(validn + Bn * Cn);            // 8*32 uint2 = 2048 B (offset 32896, 8-aligned)
    uint2* cand = topk + Bn * Cn * NPTS;                 // 8 * cap uint2
    size_t fixed = (size_t)((char*)cand - (char*)d_ws);
    int cap = (int)((ws_size - fixed) / (Bn * Cn * sizeof(uint2)));
    if (cap > 8192) cap = 8192;
    if (cap < 64) cap = 64;  // memory-safety floor; realistic n per (b,c) is ~32-300

    // Zero hist + counters (capture-legal, stream-ordered)
    hipMemsetAsync(d_ws, 0, (size_t)(Bn * Cn * NBINS + Bn * Cn) * sizeof(unsigned int), stream);

    const int per_block = 8192;                   // Sn / 256
    dim3 big_grid(Sn / per_block, Bn);            // (256, 2)

    hist_kernel<<<big_grid, 256, 0, stream>>>(logits, hist, per_block);
    cutoff_kernel<<<1, 64, 0, stream>>>(hist, cutoff, validn);
    collect_kernel<<<big_grid, 256, 0, stream>>>(logits, cutoff, cnt, cand, cap, per_block);
    select_kernel<<<Bn * Cn, 256, 0, stream>>>(cnt, cand, validn, topk, cap);
    emit_kernel<<<Bn, 128, 0, stream>>>(topk, validn, out);
}

// Round 2
// 130.032 us; speedup vs baseline: 1.3980x; 1.3980x over previous
//
#include <hip/hip_runtime.h>
#include <stdint.h>

// Problem constants (reference: B=2, C=4, SPATIAL=(128,128,128), N_PTS=32, THR=0.5)
#define Bn 2
#define Cn 4
#define Sn (128 * 128 * 128)
#define NPTS 32
#define NBINS 1025          // probs in (0.5, 1] -> one binade; (bits-0x3F000000)>>13 in [0,1024]
#define THRf 0.5f
#define SEL_LDS 4096        // LDS candidate cache in select kernel

__device__ __forceinline__ int bin_of(float p) {
    // p in (0.5, 1]; bits monotone in value within the binade (+1.0 endpoint)
    unsigned int u = __float_as_uint(p);
    return (int)((u - 0x3F000000u) >> 13);
}

// Softmax over the 4 classes at one voxel given the 4 logits; returns argmax class and its prob.
// Mirrors jax.nn.softmax: exp(x - max) / sum(exp(x - max)), sequential sum c=0..3.
__device__ __forceinline__ void softmax_argmax4(float l0, float l1, float l2, float l3,
                                                int* cm_out, float* p_out) {
    float m = fmaxf(fmaxf(l0, l1), fmaxf(l2, l3));
    float e0 = expf(l0 - m);
    float e1 = expf(l1 - m);
    float e2 = expf(l2 - m);
    float e3 = expf(l3 - m);
    float s = ((e0 + e1) + e2) + e3;
    float em = e0; int cm = 0;
    if (e1 > em) { em = e1; cm = 1; }
    if (e2 > em) { em = e2; cm = 2; }
    if (e3 > em) { em = e3; cm = 3; }
    // Only the argmax class can have p > 0.5 (probs sum to 1).
    *cm_out = cm;
    *p_out = em / s;   // identical float division to reference's p_c = e_c / s
}

// Pass 1: per-(b,c) radix histogram of candidate probs (p > 0.5). float4 loads (16 B/lane).
__global__ __launch_bounds__(256) void hist_kernel(const float* __restrict__ logits,
                                                   unsigned int* __restrict__ hist,
                                                   int per_block) {
    __shared__ unsigned int lh[Cn * NBINS];
    const int b = blockIdx.y;
    for (int j = threadIdx.x; j < Cn * NBINS; j += blockDim.x) lh[j] = 0u;
    __syncthreads();
    const float* base = logits + (size_t)b * Cn * Sn;
    const float4* s0 = (const float4*)base;
    const float4* s1 = (const float4*)(base + Sn);
    const float4* s2 = (const float4*)(base + 2 * Sn);
    const float4* s3 = (const float4*)(base + 3 * Sn);
    const int q_start = (blockIdx.x * per_block) >> 2;
    const int q_end = min(Sn >> 2, q_start + (per_block >> 2));
    for (int q = q_start + threadIdx.x; q < q_end; q += blockDim.x) {
        float4 v0 = s0[q], v1 = s1[q], v2 = s2[q], v3 = s3[q];
        const float* a0 = &v0.x; const float* a1 = &v1.x;
        const float* a2 = &v2.x; const float* a3 = &v3.x;
        #pragma unroll
        for (int k = 0; k < 4; ++k) {
            int cm; float p;
            softmax_argmax4(a0[k], a1[k], a2[k], a3[k], &cm, &p);
            if (p > THRf) atomicAdd(&lh[cm * NBINS + bin_of(p)], 1u);
        }
    }
    __syncthreads();
    unsigned int* gh = hist + (size_t)b * Cn * NBINS;
    for (int j = threadIdx.x; j < Cn * NBINS; j += blockDim.x) {
        unsigned int v = lh[j];
        if (v) atomicAdd(&gh[j], v);
    }
}

// Pass 2 (parallel): per-(b,c) block finds cutoff bin (cumulative-from-top >= 32)
// and valid_n = min(32, total). Bins loaded coalesced into LDS; per-thread chunk
// sums; thread-0 suffix scan over 256 chunk sums; crossing chunk's thread finds T.
#define CHUNK 5  // ceil(1025/256) = 5 bins per thread
__global__ __launch_bounds__(256) void cutoff_kernel(const unsigned int* __restrict__ hist,
                                                     unsigned int* __restrict__ cutoff,
                                                     unsigned int* __restrict__ validn) {
    const int bc = blockIdx.x;
    const int t = threadIdx.x;
    __shared__ unsigned int sh[NBINS];
    __shared__ unsigned int ts[256];   // per-thread chunk sum
    __shared__ unsigned int suf[256];  // sum of chunks strictly above chunk c
    __shared__ unsigned int s_total;
    const unsigned int* h = hist + (size_t)bc * NBINS;
    for (int j = t; j < NBINS; j += 256) sh[j] = h[j];
    __syncthreads();
    unsigned int cs = 0;
    const int lo = t * CHUNK;
    #pragma unroll
    for (int k = 0; k < CHUNK; ++k) {
        int bin = lo + k;
        if (bin < NBINS) cs += sh[bin];
    }
    ts[t] = cs;
    __syncthreads();
    if (t == 0) {
        unsigned int acc = 0;
        for (int c = 255; c >= 0; --c) { suf[c] = acc; acc += ts[c]; }
        s_total = acc;
        validn[bc] = acc < NPTS ? acc : NPTS;
        if (acc < NPTS) cutoff[bc] = 0u;
    }
    __syncthreads();
    const unsigned int total = s_total;
    if (total >= NPTS && suf[t] < NPTS && suf[t] + ts[t] >= NPTS) {
        // crossing happens inside this thread's chunk; scan it from the top bin down
        unsigned int acc = suf[t];
        int hi = min(lo + CHUNK - 1, NBINS - 1);
        for (int bin = hi; bin >= lo; --bin) {
            acc += sh[bin];
            if (acc >= NPTS) { cutoff[bc] = (unsigned int)bin; break; }
        }
    }
}

// Pass 3: collect all candidates with bin >= cutoff (superset of the true top-32)
__global__ __launch_bounds__(256) void collect_kernel(const float* __restrict__ logits,
                                                      const unsigned int* __restrict__ cutoff,
                                                      unsigned int* __restrict__ cnt,
                                                      uint2* __restrict__ cand,
                                                      int cap, int per_block) {
    __shared__ unsigned int cut[Cn];
    const int b = blockIdx.y;
    if (threadIdx.x < Cn) cut[threadIdx.x] = cutoff[b * Cn + threadIdx.x];
    __syncthreads();
    const float* base = logits + (size_t)b * Cn * Sn;
    const float4* s0 = (const float4*)base;
    const float4* s1 = (const float4*)(base + Sn);
    const float4* s2 = (const float4*)(base + 2 * Sn);
    const float4* s3 = (const float4*)(base + 3 * Sn);
    const int q_start = (blockIdx.x * per_block) >> 2;
    const int q_end = min(Sn >> 2, q_start + (per_block >> 2));
    for (int q = q_start + threadIdx.x; q < q_end; q += blockDim.x) {
        float4 v0 = s0[q], v1 = s1[q], v2 = s2[q], v3 = s3[q];
        const float* a0 = &v0.x; const float* a1 = &v1.x;
        const float* a2 = &v2.x; const float* a3 = &v3.x;
        #pragma unroll
        for (int k = 0; k < 4; ++k) {
            int cm; float p;
            softmax_argmax4(a0[k], a1[k], a2[k], a3[k], &cm, &p);
            if (p > THRf) {
                int bin = bin_of(p);
                if ((unsigned int)bin >= cut[cm]) {
                    int bc = b * Cn + cm;
                    unsigned int pos = atomicAdd(&cnt[bc], 1u);
                    if (pos < (unsigned int)cap)
                        cand[(size_t)bc * cap + pos] =
                            make_uint2(__float_as_uint(p), (unsigned int)(q * 4 + k));
                }
            }
        }
    }
}

// Pass 4: exact rank selection among collected candidates.
// beats(o, e): o.value > e.value, or equal value and lower index (jax top_k tie-break).
__global__ __launch_bounds__(256) void select_kernel(const unsigned int* __restrict__ cnt,
                                                     const uint2* __restrict__ cand,
                                                     const unsigned int* __restrict__ validn,
                                                     uint2* __restrict__ topk,
                                                     int cap) {
    const int bc = blockIdx.x;
    const int n = min((int)cnt[bc], cap);
    const int vn = (int)validn[bc];
    const uint2* src = cand + (size_t)bc * cap;
    __shared__ uint2 sc[SEL_LDS];
    const bool fits = (n <= SEL_LDS);
    if (fits) {
        for (int j = threadIdx.x; j < n; j += blockDim.x) sc[j] = src[j];
        __syncthreads();
    }
    for (int t = threadIdx.x; t < n; t += blockDim.x) {
        uint2 e = fits ? sc[t] : src[t];
        int rank = 0;
        if (fits) {
            for (int j = 0; j < n; ++j) {
                uint2 o = sc[j];
                rank += (int)((o.x > e.x) || (o.x == e.x && o.y < e.y));
            }
        } else {
            for (int j = 0; j < n; ++j) {
                uint2 o = src[j];
                rank += (int)((o.x > e.x) || (o.x == e.x && o.y < e.y));
            }
        }
        if (rank < vn) topk[bc * NPTS + rank] = e;
    }
}

// Pass 5: compact per-batch in class order [1,2,3,0], unravel coords, pad with -1/0.
// Output layout: coords int32 (2,128,3) flat, then labels int32 (2,128).
__global__ void emit_kernel(const uint2* __restrict__ topk,
                            const unsigned int* __restrict__ validn,
                            int* __restrict__ out) {
    const int b = blockIdx.x;
    __shared__ int pre[Cn + 1];
    if (threadIdx.x == 0) {
        int acc = 0;
        for (int oc = 0; oc < Cn; ++oc) {
            pre[oc] = acc;
            int c = (oc + 1) & 3;  // order = [1,2,3,0]
            acc += (int)validn[b * Cn + c];
        }
        pre[Cn] = acc;
    }
    __syncthreads();
    const int j = threadIdx.x;  // 0..127
    int label = -1, z = 0, y = 0, x = 0;
    if (j < pre[Cn]) {
        int oc = 0;
        while (j >= pre[oc + 1]) ++oc;
        int c = (oc + 1) & 3;
        int r = j - pre[oc];
        uint2 e = topk[(b * Cn + c) * NPTS + r];
        int idx = (int)e.y;
        z = idx >> 14;          // idx / (128*128)
        y = (idx >> 7) & 127;   // (idx / 128) % 128
        x = idx & 127;          // idx % 128
        label = c;
    }
    int* coords = out;                       // 2*128*3 = 768 ints
    int* labels = out + Bn * Cn * NPTS * 3;  // then 2*128 = 256 ints
    int base = b * Cn * NPTS + j;
    coords[base * 3 + 0] = z;
    coords[base * 3 + 1] = y;
    coords[base * 3 + 2] = x;
    labels[base] = label;
}

extern "C" void kernel_launch(void* const* d_in, const int* in_sizes, int n_in,
                              void* d_out, int out_size, void* d_ws, size_t ws_size,
                              hipStream_t stream) {
    const float* logits = (const float*)d_in[0];
    int* out = (int*)d_out;

    // Workspace layout
    unsigned int* hist = (unsigned int*)d_ws;            // 8 * 1025 u32 = 32800 B
    unsigned int* cnt = hist + Bn * Cn * NBINS;          // 8 u32
    unsigned int* cutoff = cnt + Bn * Cn;                // 8 u32
    unsigned int* validn = cutoff + Bn * Cn;             // 8 u32
    uint2* topk = (uint2*)(validn + Bn * Cn);            // 8*32 uint2 = 2048 B (offset 32896, 8-aligned)
    uint2* cand = topk + Bn * Cn * NPTS;                 // 8 * cap uint2
    size_t fixed = (size_t)((char*)cand - (char*)d_ws);
    int cap = (int)((ws_size - fixed) / (Bn * Cn * sizeof(uint2)));
    if (cap > 8192) cap = 8192;
    if (cap < 64) cap = 64;  // memory-safety floor; realistic n per (b,c) is ~32-300

    // Zero hist + counters (capture-legal, stream-ordered)
    hipMemsetAsync(d_ws, 0, (size_t)(Bn * Cn * NBINS + Bn * Cn) * sizeof(unsigned int), stream);

    const int per_block = 8192;                   // Sn / 256
    dim3 big_grid(Sn / per_block, Bn);            // (256, 2)

    hist_kernel<<<big_grid, 256, 0, stream>>>(logits, hist, per_block);
    cutoff_kernel<<<Bn * Cn, 256, 0, stream>>>(hist, cutoff, validn);
    collect_kernel<<<big_grid, 256, 0, stream>>>(logits, cutoff, cnt, cand, cap, per_block);
    select_kernel<<<Bn * Cn, 256, 0, stream>>>(cnt, cand, validn, topk, cap);
    emit_kernel<<<Bn, 128, 0, stream>>>(topk, validn, out);
}